// Round 9
// baseline (289.244 us; speedup 1.0000x reference)
//
#include <hip/hip_runtime.h>
#include <hip/hip_bf16.h>
#include <math.h>

// Transformer block B=2 T=2048 C=1024 H=16 HS=64.
// R9: attention with cooperative LDS staging (flash-attn shape).
//  pv: block = 4 waves x 32 q-rows = 128 q; per kt stage K tile (32x64) and
//      V' tile (64x32, packed as 32x128B rows) into LDS via coalesced
//      global_load_lds w16 with pre-swizzled global source (XOR slot swizzle);
//      each wave reads frags via ds_read_b128. P stays in registers
//      (pk2 + permlane32_swap). No cross-wave reduce.
//  stats: mirror structure - block = 4 waves x 32 k-rows, stages Q tiles.
//  Column-softmax (query-axis quirk), exp2-only (Q pre-scaled), dinv in V'.

#define B_   2
#define T_   2048
#define C_   1024
#define H_   16
#define HS_  64
#define NROWS 4096
#define C3   3072
#define K1C  0.1803368801111244f    // 0.125 * log2(e), folded into Q

typedef unsigned short ushort_t;
typedef __attribute__((ext_vector_type(8))) short short8;
typedef __attribute__((ext_vector_type(4))) float f32x4;
typedef __attribute__((ext_vector_type(16))) float f32x16;

__device__ __forceinline__ ushort_t f2bf(float f) {
  __hip_bfloat16 h = __float2bfloat16(f);
  ushort_t u; __builtin_memcpy(&u, &h, 2); return u;
}
__device__ __forceinline__ float bf2f(ushort_t u) {
  union { unsigned u; float f; } v; v.u = ((unsigned)u) << 16;
  return v.f;
}
__device__ __forceinline__ unsigned pk2(float a, float b) {
  __hip_bfloat162 t = __float22bfloat162_rn(make_float2(a, b));
  unsigned u; __builtin_memcpy(&u, &t, 4); return u;
}
__device__ __forceinline__ short8 mk8(unsigned a, unsigned b, unsigned c, unsigned d) {
  union { unsigned u[4]; short8 s; } t;
  t.u[0] = a; t.u[1] = b; t.u[2] = c; t.u[3] = d; return t.s;
}
__device__ __forceinline__ void pl32swap(unsigned &a, unsigned &b) {
  asm("v_permlane32_swap_b32 %0, %1" : "+v"(a), "+v"(b));
}
__device__ __forceinline__ f32x4 mfma16(short8 a, short8 b, f32x4 c) {
  return __builtin_amdgcn_mfma_f32_16x16x32_bf16(a, b, c, 0, 0, 0);
}
__device__ __forceinline__ f32x16 mfma32(short8 a, short8 b, f32x16 c) {
  return __builtin_amdgcn_mfma_f32_32x32x16_bf16(a, b, c, 0, 0, 0);
}
typedef const __attribute__((address_space(1))) void g_void;
typedef __attribute__((address_space(3))) void l_void;
__device__ __forceinline__ void gl_lds16(const void* g, void* l) {
  __builtin_amdgcn_global_load_lds((g_void*)g, (l_void*)l, 16, 0, 0);
}

// ---------------- LayerNorm (f32 in -> bf16 out) ----------------
__global__ __launch_bounds__(256) void ln_bf16(
    const float* __restrict__ x, const float* __restrict__ g,
    const float* __restrict__ b, ushort_t* __restrict__ out) {
  int row = blockIdx.x;
  const float* xr = x + (size_t)row * C_;
  int t = threadIdx.x;
  float4 v = ((const float4*)xr)[t];
  float s  = v.x + v.y + v.z + v.w;
  float ss = v.x*v.x + v.y*v.y + v.z*v.z + v.w*v.w;
  #pragma unroll
  for (int off = 32; off > 0; off >>= 1) {
    s  += __shfl_down(s, off);
    ss += __shfl_down(ss, off);
  }
  __shared__ float red[2][4];
  int wid = t >> 6, lane = t & 63;
  if (lane == 0) { red[0][wid] = s; red[1][wid] = ss; }
  __syncthreads();
  if (t == 0) {
    float a = 0, c = 0;
    for (int i = 0; i < 4; i++) { a += red[0][i]; c += red[1][i]; }
    red[0][0] = a; red[1][0] = c;
  }
  __syncthreads();
  float mean = red[0][0] * (1.0f / C_);
  float var  = red[1][0] * (1.0f / C_) - mean * mean;
  float r = rsqrtf(var + 1e-5f);
  float4 gv = ((const float4*)g)[t];
  float4 bv = ((const float4*)b)[t];
  ushort4 o;
  o.x = f2bf((v.x - mean) * r * gv.x + bv.x);
  o.y = f2bf((v.y - mean) * r * gv.y + bv.y);
  o.z = f2bf((v.z - mean) * r * gv.z + bv.z);
  o.w = f2bf((v.w - mean) * r * gv.w + bv.w);
  ((ushort4*)(out + (size_t)row * C_))[t] = o;
}

// ---- Wq,Wk,Wv (H,C,HS) f32 -> concatenated (3072, 1024) bf16 N-major ----
__global__ __launch_bounds__(256) void conv_wqkv3(
    const float* __restrict__ Wq, const float* __restrict__ Wk,
    const float* __restrict__ Wv, ushort_t* __restrict__ Wt) {
  int idx = blockIdx.x * 256 + threadIdx.x;
  int n = idx >> 10, c = idx & 1023;
  int sel = n >> 10, nn = n & 1023;
  const float* W = (sel == 0) ? Wq : ((sel == 1) ? Wk : Wv);
  Wt[idx] = f2bf(W[((size_t)(nn >> 6) * C_ + c) * HS_ + (nn & 63)]);
}

// ---- Wo,W1,W2 (K,N) f32 -> three contiguous (N,K) bf16 blocks ----
__global__ __launch_bounds__(256) void conv_wt3(
    const float* __restrict__ W0, const float* __restrict__ W1,
    const float* __restrict__ W2, ushort_t* __restrict__ Wt) {
  int idx = blockIdx.x * 256 + threadIdx.x;
  int sel = idx >> 20, rem = idx & 1048575;
  int n = rem >> 10, k = rem & 1023;
  const float* W = (sel == 0) ? W0 : ((sel == 1) ? W1 : W2);
  Wt[idx] = f2bf(W[(size_t)k * C_ + n]);
}

__global__ __launch_bounds__(256) void bias_cat(
    const float* __restrict__ bq, const float* __restrict__ bk,
    const float* __restrict__ bv, float* __restrict__ out) {
  int i = blockIdx.x * 256 + threadIdx.x;
  if (i < 3072)
    out[i] = (i < 1024) ? bq[i] : ((i < 2048) ? bk[i - 1024] : bv[i - 2048]);
}

// -------- GEMM 128x128 tile (QKV, N=3072); Q third scaled by K1C --------
__global__ __launch_bounds__(256) void gemm128(
    const ushort_t* __restrict__ A, const ushort_t* __restrict__ Bt,
    const float* __restrict__ bias, ushort_t* __restrict__ Cm,
    int M, int N, int K) {
  __shared__ ushort_t As[128 * 32];
  __shared__ ushort_t Bs[128 * 32];
  int t = threadIdx.x;
  int m0 = blockIdx.y * 128, n0 = blockIdx.x * 128;
  int w = t >> 6, l = t & 63;
  int wr = w >> 1, wc = w & 1;
  int lo = l & 15, hi = l >> 4;
  f32x4 acc[4][4] = {};
  int srow = t >> 2, scol = (t & 3) * 8;
  const ushort_t* Ag = A  + (size_t)(m0 + srow) * K + scol;
  const ushort_t* Bg = Bt + (size_t)(n0 + srow) * K + scol;
  ushort_t* AsP = As + t * 8;
  ushort_t* BsP = Bs + t * 8;
  for (int k0 = 0; k0 < K; k0 += 32) {
    gl_lds16(Ag + k0,          AsP);
    gl_lds16(Ag + 64 * K + k0, AsP + 64 * 32);
    gl_lds16(Bg + k0,          BsP);
    gl_lds16(Bg + 64 * K + k0, BsP + 64 * 32);
    __syncthreads();
    short8 af[4], bfr[4];
    #pragma unroll
    for (int i = 0; i < 4; i++)
      af[i] = *(const short8*)&As[(wr * 64 + i * 16 + lo) * 32 + hi * 8];
    #pragma unroll
    for (int j = 0; j < 4; j++)
      bfr[j] = *(const short8*)&Bs[(wc * 64 + j * 16 + lo) * 32 + hi * 8];
    #pragma unroll
    for (int i = 0; i < 4; i++)
      #pragma unroll
      for (int j = 0; j < 4; j++)
        acc[i][j] = mfma16(af[i], bfr[j], acc[i][j]);
    __syncthreads();
  }
  float qs = (n0 < C_) ? K1C : 1.0f;
  #pragma unroll
  for (int i = 0; i < 4; i++) {
    int m = m0 + wr * 64 + i * 16 + hi * 4;
    #pragma unroll
    for (int j = 0; j < 4; j++) {
      int n = n0 + wc * 64 + j * 16 + lo;
      float bv = bias[n];
      #pragma unroll
      for (int r = 0; r < 4; r++)
        Cm[(size_t)(m + r) * N + n] = f2bf((acc[i][j][r] + bv) * qs);
    }
  }
}

// ---------------- GEMM 128x64 tile (N=1024 GEMMs) ----------------
template<int OUT_BF16, int RELU, int HAS_RES>
__global__ __launch_bounds__(256) void gemm64(
    const ushort_t* __restrict__ A, const ushort_t* __restrict__ Bt,
    const float* __restrict__ bias, const float* __restrict__ res,
    void* __restrict__ Cm, int M, int N, int K) {
  __shared__ ushort_t As[128 * 32];
  __shared__ ushort_t Bs[64 * 32];
  int t = threadIdx.x;
  int m0 = blockIdx.y * 128, n0 = blockIdx.x * 64;
  int w = t >> 6, l = t & 63;
  int wr = w >> 1, wc = w & 1;
  int lo = l & 15, hi = l >> 4;
  f32x4 acc[4][2] = {};
  int srow = t >> 2, scol = (t & 3) * 8;
  const ushort_t* Ag = A  + (size_t)(m0 + srow) * K + scol;
  const ushort_t* Bg = Bt + (size_t)(n0 + srow) * K + scol;
  ushort_t* AsP = As + t * 8;
  ushort_t* BsP = Bs + t * 8;
  for (int k0 = 0; k0 < K; k0 += 32) {
    gl_lds16(Ag + k0,          AsP);
    gl_lds16(Ag + 64 * K + k0, AsP + 64 * 32);
    gl_lds16(Bg + k0,          BsP);
    __syncthreads();
    short8 af[4], bfr[2];
    #pragma unroll
    for (int i = 0; i < 4; i++)
      af[i] = *(const short8*)&As[(wr * 64 + i * 16 + lo) * 32 + hi * 8];
    #pragma unroll
    for (int j = 0; j < 2; j++)
      bfr[j] = *(const short8*)&Bs[(wc * 32 + j * 16 + lo) * 32 + hi * 8];
    #pragma unroll
    for (int i = 0; i < 4; i++)
      #pragma unroll
      for (int j = 0; j < 2; j++)
        acc[i][j] = mfma16(af[i], bfr[j], acc[i][j]);
    __syncthreads();
  }
  #pragma unroll
  for (int i = 0; i < 4; i++) {
    int m = m0 + wr * 64 + i * 16 + hi * 4;
    #pragma unroll
    for (int j = 0; j < 2; j++) {
      int n = n0 + wc * 32 + j * 16 + lo;
      float bv = bias[n];
      #pragma unroll
      for (int r = 0; r < 4; r++) {
        float v = acc[i][j][r] + bv;
        if (HAS_RES) v += res[(size_t)(m + r) * N + n];
        if (RELU) v = fmaxf(v, 0.f);
        if (OUT_BF16) ((ushort_t*)Cm)[(size_t)(m + r) * N + n] = f2bf(v);
        else          ((float*)Cm)[(size_t)(m + r) * N + n] = v;
      }
    }
  }
}

// ---- stats: block = 4 waves x 32 k-rows = 128 k. Q tiles staged in LDS ----
// dinv[k] = 1/sum_{q>=k} exp2(s'). grid (kb 16, bh 32).
__global__ __launch_bounds__(256) void attn_stats(
    const ushort_t* __restrict__ QKV, float* __restrict__ dinv) {
  int kb = blockIdx.x, bh = blockIdx.y;
  int b = bh >> 4, h = bh & 15;
  int t = threadIdx.x, w = t >> 6, l = t & 63, l31 = l & 31, hi32 = l >> 5;
  __shared__ ushort_t Qs[32 * 64];   // 4KB: 32 q-rows x 128B, XOR-slot swizzled
  const ushort_t* Qb = QKV + (size_t)b * T_ * C3 + h * HS_;
  const ushort_t* Kb = Qb + C_;
  int k0w = kb * 128 + w * 32;
  // own K rows as A-frags (strided global, once per block)
  short8 ka[4];
  #pragma unroll
  for (int c = 0; c < 4; c++)
    ka[c] = *(const short8*)(Kb + (size_t)(k0w + l31) * C3 + c * 16 + hi32 * 8);
  float s[16];
  #pragma unroll
  for (int r = 0; r < 16; r++) s[r] = 0.f;

  int sr = t >> 3, sslot = t & 7, su = sslot ^ (sr & 7);
  int dqt = (k0w >> 5);              // wave's diagonal q-tile
  for (int qt = kb * 4; qt < 64; qt++) {
    gl_lds16(Qb + (size_t)(qt * 32 + sr) * C3 + su * 8, &Qs[t * 8]);
    __syncthreads();
    if (qt >= dqt) {
      short8 qf[4];
      #pragma unroll
      for (int c = 0; c < 4; c++)
        qf[c] = *(const short8*)&Qs[l31 * 64 + ((c * 2 + hi32) ^ (l31 & 7)) * 8];
      f32x16 d = {};
      #pragma unroll
      for (int c = 0; c < 4; c++) d = mfma32(ka[c], qf[c], d);
      if (qt == dqt) {               // diagonal: mask q >= k
        int q = qt * 32 + l31;
        #pragma unroll
        for (int r = 0; r < 16; r++) {
          int k = k0w + (r & 3) + 8 * (r >> 2) + 4 * hi32;
          s[r] += (q >= k) ? exp2f(d[r]) : 0.f;
        }
      } else {
        #pragma unroll
        for (int r = 0; r < 16; r++) s[r] += exp2f(d[r]);
      }
    }
    __syncthreads();
  }
  #pragma unroll
  for (int off = 1; off < 32; off <<= 1)
    #pragma unroll
    for (int r = 0; r < 16; r++)
      s[r] += __shfl_xor(s[r], off);
  if (l31 == 0) {
    #pragma unroll
    for (int r = 0; r < 16; r++) {
      int k = k0w + (r & 3) + 8 * (r >> 2) + 4 * hi32;
      dinv[(size_t)bh * T_ + k] = 1.0f / s[r];
    }
  }
}

// ---- V' = V * dinv, per-head transpose to (bh, HS, T) ----
__global__ __launch_bounds__(256) void transpose_v(
    const ushort_t* __restrict__ QKV, const float* __restrict__ dinv,
    ushort_t* __restrict__ Vt) {
  int t0 = blockIdx.x * 64;
  int bh = blockIdx.y; int b = bh >> 4, h = bh & 15;
  __shared__ ushort_t tile[64][65];
  int tid = threadIdx.x;
  #pragma unroll
  for (int i = 0; i < 16; i++) {
    int idx = i * 256 + tid;
    int tt = idx >> 6, dd = idx & 63;
    float v = bf2f(QKV[(size_t)(b * T_ + t0 + tt) * C3 + 2 * C_ + h * HS_ + dd]);
    tile[tt][dd] = f2bf(v * dinv[(size_t)bh * T_ + t0 + tt]);
  }
  __syncthreads();
  #pragma unroll
  for (int i = 0; i < 16; i++) {
    int idx = i * 256 + tid;
    int dd = idx >> 6, tt = idx & 63;
    Vt[((size_t)(bh * HS_ + dd)) * T_ + t0 + tt] = tile[tt][dd];
  }
}

// ---- PV: block = 4 waves x 32 q-rows = 128 q. K/V' tiles staged in LDS ----
// att[q,d] = sum_{k<=q} exp2(s') * V'[k,d]. grid (qb 16, bh 32), big-first.
__global__ __launch_bounds__(256) void attn_pv(
    const ushort_t* __restrict__ QKV, const ushort_t* __restrict__ Vt,
    ushort_t* __restrict__ att) {
  int qb = 15 - blockIdx.x, bh = blockIdx.y;
  int b = bh >> 4, h = bh & 15;
  int t = threadIdx.x, w = t >> 6, l = t & 63, l31 = l & 31, hi32 = l >> 5;
  __shared__ ushort_t Ks[32 * 64];   // 4KB: 32 k-rows x 128B, swizzled
  __shared__ ushort_t Vs[32 * 64];   // 4KB: row j = d-rows {j, j+32}, swizzled
  const ushort_t* Qb = QKV + (size_t)b * T_ * C3 + h * HS_;
  const ushort_t* Kb = Qb + C_;
  const ushort_t* Vb = Vt + (size_t)bh * HS_ * T_;
  int q0w = qb * 128 + w * 32;
  short8 qf[4];
  #pragma unroll
  for (int c = 0; c < 4; c++)
    qf[c] = *(const short8*)(Qb + (size_t)(q0w + l31) * C3 + c * 16 + hi32 * 8);
  f32x16 o0 = {}, o1 = {};
  int nkt = qb * 4 + 4;
  int dkt = q0w >> 5;                // wave's diagonal k-tile

  int sr = t >> 3, sslot = t & 7, su = sslot ^ (sr & 7);
  int vdh = su >> 2, vc2 = su & 3;
  for (int kt = 0; kt < nkt; kt++) {
    gl_lds16(Kb + (size_t)(kt * 32 + sr) * C3 + su * 8, &Ks[t * 8]);
    gl_lds16(Vb + (size_t)(vdh * 32 + sr) * T_ + kt * 32 + vc2 * 8, &Vs[t * 8]);
    __syncthreads();
    if (kt <= dkt) {
      short8 ka[4], vf[4];
      #pragma unroll
      for (int c = 0; c < 4; c++)
        ka[c] = *(const short8*)&Ks[l31 * 64 + ((c * 2 + hi32) ^ (l31 & 7)) * 8];
      #pragma unroll
      for (int i = 0; i < 4; i++) {
        int u = (i & 1) * 4 + (i >> 1) * 2 + hi32;   // dh*4 + c16*2 + hi32
        vf[i] = *(const short8*)&Vs[l31 * 64 + (u ^ (l31 & 7)) * 8];
      }
      f32x16 sacc = {};
      #pragma unroll
      for (int c = 0; c < 4; c++) sacc = mfma32(ka[c], qf[c], sacc);
      float e[16];
      if (kt == dkt) {               // diagonal: mask k <= q
        int q = q0w + l31;
        #pragma unroll
        for (int r = 0; r < 16; r++) {
          int k = kt * 32 + (r & 3) + 8 * (r >> 2) + 4 * hi32;
          e[r] = (k <= q) ? exp2f(sacc[r]) : 0.f;
        }
      } else {
        #pragma unroll
        for (int r = 0; r < 16; r++) e[r] = exp2f(sacc[r]);
      }
      unsigned u[8];
      #pragma unroll
      for (int j = 0; j < 8; j++) u[j] = pk2(e[2 * j], e[2 * j + 1]);
      pl32swap(u[0], u[2]); pl32swap(u[1], u[3]);
      pl32swap(u[4], u[6]); pl32swap(u[5], u[7]);
      short8 pa0 = mk8(u[0], u[1], u[2], u[3]);
      short8 pa1 = mk8(u[4], u[5], u[6], u[7]);
      o0 = mfma32(pa0, vf[0], o0);   // k 0..15,  d 0..31
      o1 = mfma32(pa0, vf[1], o1);   // k 0..15,  d 32..63
      o0 = mfma32(pa1, vf[2], o0);   // k 16..31, d 0..31
      o1 = mfma32(pa1, vf[3], o1);
    }
    __syncthreads();
  }

  #pragma unroll
  for (int r = 0; r < 16; r++) {
    int q = q0w + (r & 3) + 8 * (r >> 2) + 4 * hi32;
    size_t base = (size_t)(b * T_ + q) * C_ + h * HS_;
    att[base + l31]      = f2bf(o0[r]);
    att[base + 32 + l31] = f2bf(o1[r]);
  }
}

extern "C" void kernel_launch(void* const* d_in, const int* in_sizes, int n_in,
                              void* d_out, int out_size, void* d_ws, size_t ws_size,
                              hipStream_t stream) {
  const float* x   = (const float*)d_in[0];
  const float* Wq  = (const float*)d_in[1];
  const float* bq  = (const float*)d_in[2];
  const float* Wk  = (const float*)d_in[3];
  const float* bk  = (const float*)d_in[4];
  const float* Wv  = (const float*)d_in[5];
  const float* bv  = (const float*)d_in[6];
  const float* Wo  = (const float*)d_in[7];
  const float* bo  = (const float*)d_in[8];
  const float* g1  = (const float*)d_in[9];
  const float* b1  = (const float*)d_in[10];
  const float* g2  = (const float*)d_in[11];
  const float* b2  = (const float*)d_in[12];
  const float* W1  = (const float*)d_in[13];
  const float* bf1 = (const float*)d_in[14];
  const float* W2  = (const float*)d_in[15];
  const float* bf2 = (const float*)d_in[16];
  float* out = (float*)d_out;

  char* base = (char*)d_ws;
  const size_t MB = 1 << 20;
  ushort_t* QKVb  = (ushort_t*)(base);            // 24MB
  ushort_t* hb    = (ushort_t*)(base + 24 * MB);  // 8MB: LN1 out -> att
  ushort_t* Vt    = (ushort_t*)(base + 32 * MB);  // 8MB: V' -> f1b
  float*    y     = (float*)   (base + 40 * MB);  // 16MB
  ushort_t* Wqkvt = (ushort_t*)(base + 56 * MB);  // 6MB
  ushort_t* Wot   = (ushort_t*)(base + 62 * MB);  // 2MB
  ushort_t* W1t   = (ushort_t*)(base + 64 * MB);  // 2MB
  ushort_t* W2t   = (ushort_t*)(base + 66 * MB);  // 2MB
  float*    bqkv  = (float*)   (base + 68 * MB);  // 12KB
  float*    dinv  = (float*)   (base + 68 * MB + 65536); // 256KB

  conv_wqkv3<<<12288, 256, 0, stream>>>(Wq, Wk, Wv, Wqkvt);
  conv_wt3  <<<12288, 256, 0, stream>>>(Wo, W1, W2, Wot);
  bias_cat  <<<12, 256, 0, stream>>>(bq, bk, bv, bqkv);

  ln_bf16<<<NROWS, 256, 0, stream>>>(x, g1, b1, hb);

  gemm128<<<dim3(C3 / 128, NROWS / 128), 256, 0, stream>>>(
      hb, Wqkvt, bqkv, QKVb, NROWS, C3, C_);

  attn_stats<<<dim3(16, 32), 256, 0, stream>>>(QKVb, dinv);
  transpose_v<<<dim3(T_ / 64, 32), 256, 0, stream>>>(QKVb, dinv, Vt);
  ushort_t* attb = hb;
  attn_pv<<<dim3(16, 32), 256, 0, stream>>>(QKVb, Vt, attb);

  dim3 g64(C_ / 64, NROWS / 128);
  gemm64<0,0,1><<<g64, 256, 0, stream>>>(attb, Wot, bo, x, y, NROWS, C_, C_);

  ushort_t* h2b = QKVb;
  ln_bf16<<<NROWS, 256, 0, stream>>>(y, g2, b2, h2b);
  ushort_t* f1b = Vt;
  gemm64<1,1,0><<<g64, 256, 0, stream>>>(h2b, W1t, bf1, nullptr, f1b, NROWS, C_, C_);
  gemm64<0,0,1><<<g64, 256, 0, stream>>>(f1b, W2t, bf2, y, out, NROWS, C_, C_);
}

// Round 10
// 276.738 us; speedup vs baseline: 1.0452x; 1.0452x over previous
//
#include <hip/hip_runtime.h>
#include <hip/hip_bf16.h>
#include <math.h>

// Transformer block B=2 T=2048 C=1024 H=16 HS=64.
// R10: R9's staged attention + PROPER 2-phase pipeline (T3/T4):
//  double-buffered LDS tiles, prefetch kt+1 issued before compute(kt),
//  counted s_waitcnt vmcnt(2) (never 0 mid-loop), raw s_barrier with
//  sched_barrier(0) guards. Math/swizzles identical to R9 (absmax-verified).
//  Column-softmax (query-axis quirk), exp2-only (Q pre-scaled), dinv in V'.

#define B_   2
#define T_   2048
#define C_   1024
#define H_   16
#define HS_  64
#define NROWS 4096
#define C3   3072
#define K1C  0.1803368801111244f    // 0.125 * log2(e), folded into Q

typedef unsigned short ushort_t;
typedef __attribute__((ext_vector_type(8))) short short8;
typedef __attribute__((ext_vector_type(4))) float f32x4;
typedef __attribute__((ext_vector_type(16))) float f32x16;

__device__ __forceinline__ ushort_t f2bf(float f) {
  __hip_bfloat16 h = __float2bfloat16(f);
  ushort_t u; __builtin_memcpy(&u, &h, 2); return u;
}
__device__ __forceinline__ float bf2f(ushort_t u) {
  union { unsigned u; float f; } v; v.u = ((unsigned)u) << 16;
  return v.f;
}
__device__ __forceinline__ unsigned pk2(float a, float b) {
  __hip_bfloat162 t = __float22bfloat162_rn(make_float2(a, b));
  unsigned u; __builtin_memcpy(&u, &t, 4); return u;
}
__device__ __forceinline__ short8 mk8(unsigned a, unsigned b, unsigned c, unsigned d) {
  union { unsigned u[4]; short8 s; } t;
  t.u[0] = a; t.u[1] = b; t.u[2] = c; t.u[3] = d; return t.s;
}
__device__ __forceinline__ void pl32swap(unsigned &a, unsigned &b) {
  asm("v_permlane32_swap_b32 %0, %1" : "+v"(a), "+v"(b));
}
__device__ __forceinline__ f32x4 mfma16(short8 a, short8 b, f32x4 c) {
  return __builtin_amdgcn_mfma_f32_16x16x32_bf16(a, b, c, 0, 0, 0);
}
__device__ __forceinline__ f32x16 mfma32(short8 a, short8 b, f32x16 c) {
  return __builtin_amdgcn_mfma_f32_32x32x16_bf16(a, b, c, 0, 0, 0);
}
typedef const __attribute__((address_space(1))) void g_void;
typedef __attribute__((address_space(3))) void l_void;
__device__ __forceinline__ void gl_lds16(const void* g, void* l) {
  __builtin_amdgcn_global_load_lds((g_void*)g, (l_void*)l, 16, 0, 0);
}

// ---------------- LayerNorm (f32 in -> bf16 out) ----------------
__global__ __launch_bounds__(256) void ln_bf16(
    const float* __restrict__ x, const float* __restrict__ g,
    const float* __restrict__ b, ushort_t* __restrict__ out) {
  int row = blockIdx.x;
  const float* xr = x + (size_t)row * C_;
  int t = threadIdx.x;
  float4 v = ((const float4*)xr)[t];
  float s  = v.x + v.y + v.z + v.w;
  float ss = v.x*v.x + v.y*v.y + v.z*v.z + v.w*v.w;
  #pragma unroll
  for (int off = 32; off > 0; off >>= 1) {
    s  += __shfl_down(s, off);
    ss += __shfl_down(ss, off);
  }
  __shared__ float red[2][4];
  int wid = t >> 6, lane = t & 63;
  if (lane == 0) { red[0][wid] = s; red[1][wid] = ss; }
  __syncthreads();
  if (t == 0) {
    float a = 0, c = 0;
    for (int i = 0; i < 4; i++) { a += red[0][i]; c += red[1][i]; }
    red[0][0] = a; red[1][0] = c;
  }
  __syncthreads();
  float mean = red[0][0] * (1.0f / C_);
  float var  = red[1][0] * (1.0f / C_) - mean * mean;
  float r = rsqrtf(var + 1e-5f);
  float4 gv = ((const float4*)g)[t];
  float4 bv = ((const float4*)b)[t];
  ushort4 o;
  o.x = f2bf((v.x - mean) * r * gv.x + bv.x);
  o.y = f2bf((v.y - mean) * r * gv.y + bv.y);
  o.z = f2bf((v.z - mean) * r * gv.z + bv.z);
  o.w = f2bf((v.w - mean) * r * gv.w + bv.w);
  ((ushort4*)(out + (size_t)row * C_))[t] = o;
}

// ---- Wq,Wk,Wv (H,C,HS) f32 -> concatenated (3072, 1024) bf16 N-major ----
__global__ __launch_bounds__(256) void conv_wqkv3(
    const float* __restrict__ Wq, const float* __restrict__ Wk,
    const float* __restrict__ Wv, ushort_t* __restrict__ Wt) {
  int idx = blockIdx.x * 256 + threadIdx.x;
  int n = idx >> 10, c = idx & 1023;
  int sel = n >> 10, nn = n & 1023;
  const float* W = (sel == 0) ? Wq : ((sel == 1) ? Wk : Wv);
  Wt[idx] = f2bf(W[((size_t)(nn >> 6) * C_ + c) * HS_ + (nn & 63)]);
}

// ---- Wo,W1,W2 (K,N) f32 -> three contiguous (N,K) bf16 blocks ----
__global__ __launch_bounds__(256) void conv_wt3(
    const float* __restrict__ W0, const float* __restrict__ W1,
    const float* __restrict__ W2, ushort_t* __restrict__ Wt) {
  int idx = blockIdx.x * 256 + threadIdx.x;
  int sel = idx >> 20, rem = idx & 1048575;
  int n = rem >> 10, k = rem & 1023;
  const float* W = (sel == 0) ? W0 : ((sel == 1) ? W1 : W2);
  Wt[idx] = f2bf(W[(size_t)k * C_ + n]);
}

__global__ __launch_bounds__(256) void bias_cat(
    const float* __restrict__ bq, const float* __restrict__ bk,
    const float* __restrict__ bv, float* __restrict__ out) {
  int i = blockIdx.x * 256 + threadIdx.x;
  if (i < 3072)
    out[i] = (i < 1024) ? bq[i] : ((i < 2048) ? bk[i - 1024] : bv[i - 2048]);
}

// -------- GEMM 128x128 tile (QKV, N=3072); Q third scaled by K1C --------
__global__ __launch_bounds__(256) void gemm128(
    const ushort_t* __restrict__ A, const ushort_t* __restrict__ Bt,
    const float* __restrict__ bias, ushort_t* __restrict__ Cm,
    int M, int N, int K) {
  __shared__ ushort_t As[128 * 32];
  __shared__ ushort_t Bs[128 * 32];
  int t = threadIdx.x;
  int m0 = blockIdx.y * 128, n0 = blockIdx.x * 128;
  int w = t >> 6, l = t & 63;
  int wr = w >> 1, wc = w & 1;
  int lo = l & 15, hi = l >> 4;
  f32x4 acc[4][4] = {};
  int srow = t >> 2, scol = (t & 3) * 8;
  const ushort_t* Ag = A  + (size_t)(m0 + srow) * K + scol;
  const ushort_t* Bg = Bt + (size_t)(n0 + srow) * K + scol;
  ushort_t* AsP = As + t * 8;
  ushort_t* BsP = Bs + t * 8;
  for (int k0 = 0; k0 < K; k0 += 32) {
    gl_lds16(Ag + k0,          AsP);
    gl_lds16(Ag + 64 * K + k0, AsP + 64 * 32);
    gl_lds16(Bg + k0,          BsP);
    gl_lds16(Bg + 64 * K + k0, BsP + 64 * 32);
    __syncthreads();
    short8 af[4], bfr[4];
    #pragma unroll
    for (int i = 0; i < 4; i++)
      af[i] = *(const short8*)&As[(wr * 64 + i * 16 + lo) * 32 + hi * 8];
    #pragma unroll
    for (int j = 0; j < 4; j++)
      bfr[j] = *(const short8*)&Bs[(wc * 64 + j * 16 + lo) * 32 + hi * 8];
    #pragma unroll
    for (int i = 0; i < 4; i++)
      #pragma unroll
      for (int j = 0; j < 4; j++)
        acc[i][j] = mfma16(af[i], bfr[j], acc[i][j]);
    __syncthreads();
  }
  float qs = (n0 < C_) ? K1C : 1.0f;
  #pragma unroll
  for (int i = 0; i < 4; i++) {
    int m = m0 + wr * 64 + i * 16 + hi * 4;
    #pragma unroll
    for (int j = 0; j < 4; j++) {
      int n = n0 + wc * 64 + j * 16 + lo;
      float bv = bias[n];
      #pragma unroll
      for (int r = 0; r < 4; r++)
        Cm[(size_t)(m + r) * N + n] = f2bf((acc[i][j][r] + bv) * qs);
    }
  }
}

// ---------------- GEMM 128x64 tile (N=1024 GEMMs) ----------------
template<int OUT_BF16, int RELU, int HAS_RES>
__global__ __launch_bounds__(256) void gemm64(
    const ushort_t* __restrict__ A, const ushort_t* __restrict__ Bt,
    const float* __restrict__ bias, const float* __restrict__ res,
    void* __restrict__ Cm, int M, int N, int K) {
  __shared__ ushort_t As[128 * 32];
  __shared__ ushort_t Bs[64 * 32];
  int t = threadIdx.x;
  int m0 = blockIdx.y * 128, n0 = blockIdx.x * 64;
  int w = t >> 6, l = t & 63;
  int wr = w >> 1, wc = w & 1;
  int lo = l & 15, hi = l >> 4;
  f32x4 acc[4][2] = {};
  int srow = t >> 2, scol = (t & 3) * 8;
  const ushort_t* Ag = A  + (size_t)(m0 + srow) * K + scol;
  const ushort_t* Bg = Bt + (size_t)(n0 + srow) * K + scol;
  ushort_t* AsP = As + t * 8;
  ushort_t* BsP = Bs + t * 8;
  for (int k0 = 0; k0 < K; k0 += 32) {
    gl_lds16(Ag + k0,          AsP);
    gl_lds16(Ag + 64 * K + k0, AsP + 64 * 32);
    gl_lds16(Bg + k0,          BsP);
    __syncthreads();
    short8 af[4], bfr[2];
    #pragma unroll
    for (int i = 0; i < 4; i++)
      af[i] = *(const short8*)&As[(wr * 64 + i * 16 + lo) * 32 + hi * 8];
    #pragma unroll
    for (int j = 0; j < 2; j++)
      bfr[j] = *(const short8*)&Bs[(wc * 32 + j * 16 + lo) * 32 + hi * 8];
    #pragma unroll
    for (int i = 0; i < 4; i++)
      #pragma unroll
      for (int j = 0; j < 2; j++)
        acc[i][j] = mfma16(af[i], bfr[j], acc[i][j]);
    __syncthreads();
  }
  #pragma unroll
  for (int i = 0; i < 4; i++) {
    int m = m0 + wr * 64 + i * 16 + hi * 4;
    #pragma unroll
    for (int j = 0; j < 2; j++) {
      int n = n0 + wc * 32 + j * 16 + lo;
      float bv = bias[n];
      #pragma unroll
      for (int r = 0; r < 4; r++) {
        float v = acc[i][j][r] + bv;
        if (HAS_RES) v += res[(size_t)(m + r) * N + n];
        if (RELU) v = fmaxf(v, 0.f);
        if (OUT_BF16) ((ushort_t*)Cm)[(size_t)(m + r) * N + n] = f2bf(v);
        else          ((float*)Cm)[(size_t)(m + r) * N + n] = v;
      }
    }
  }
}

// ---- stats: block = 4 waves x 32 k-rows. Q tiles double-buffered in LDS ----
// dinv[k] = 1/sum_{q>=k} exp2(s'). 1-D grid 512: kb = bid&15 (kb=0 big first).
__global__ __launch_bounds__(256) void attn_stats(
    const ushort_t* __restrict__ QKV, float* __restrict__ dinv) {
  int bid = blockIdx.x;
  int kb = bid & 15, bh = bid >> 4;
  int b = bh >> 4, h = bh & 15;
  int t = threadIdx.x, w = t >> 6, l = t & 63, l31 = l & 31, hi32 = l >> 5;
  __shared__ ushort_t Qs[2][32 * 64];   // 8KB, double-buffered
  const ushort_t* Qb = QKV + (size_t)b * T_ * C3 + h * HS_;
  const ushort_t* Kb = Qb + C_;
  int k0w = kb * 128 + w * 32;
  short8 ka[4];
  #pragma unroll
  for (int c = 0; c < 4; c++)
    ka[c] = *(const short8*)(Kb + (size_t)(k0w + l31) * C3 + c * 16 + hi32 * 8);
  float s[16];
  #pragma unroll
  for (int r = 0; r < 16; r++) s[r] = 0.f;

  int sr = t >> 3, slot = t & 7, su = slot ^ (sr & 7);
  const ushort_t* Qsrc = Qb + (size_t)sr * C3 + su * 8;   // + qt*32*C3
  int qt0 = kb * 4, cnt = 64 - qt0;
  int dqt = qt0 + w;                 // wave's diagonal q-tile

  gl_lds16(Qsrc + (size_t)qt0 * 32 * C3, &Qs[0][t * 8]);
  for (int i = 0; i < cnt; i++) {
    int qt = qt0 + i, cur = i & 1;
    if (i + 1 < cnt) {
      gl_lds16(Qsrc + (size_t)(qt + 1) * 32 * C3, &Qs[cur ^ 1][t * 8]);
      asm volatile("s_waitcnt vmcnt(1)");
    } else {
      asm volatile("s_waitcnt vmcnt(0)");
    }
    __builtin_amdgcn_s_barrier();
    __builtin_amdgcn_sched_barrier(0);
    if (qt >= dqt) {
      short8 qf[4];
      #pragma unroll
      for (int c = 0; c < 4; c++)
        qf[c] = *(const short8*)&Qs[cur][l31 * 64 + ((c * 2 + hi32) ^ (l31 & 7)) * 8];
      f32x16 d = {};
      #pragma unroll
      for (int c = 0; c < 4; c++) d = mfma32(ka[c], qf[c], d);
      if (qt == dqt) {               // diagonal: mask q >= k
        int q = qt * 32 + l31;
        #pragma unroll
        for (int r = 0; r < 16; r++) {
          int k = k0w + (r & 3) + 8 * (r >> 2) + 4 * hi32;
          s[r] += (q >= k) ? exp2f(d[r]) : 0.f;
        }
      } else {
        #pragma unroll
        for (int r = 0; r < 16; r++) s[r] += exp2f(d[r]);
      }
    }
    __builtin_amdgcn_sched_barrier(0);
    __builtin_amdgcn_s_barrier();
    __builtin_amdgcn_sched_barrier(0);
  }
  #pragma unroll
  for (int off = 1; off < 32; off <<= 1)
    #pragma unroll
    for (int r = 0; r < 16; r++)
      s[r] += __shfl_xor(s[r], off);
  if (l31 == 0) {
    #pragma unroll
    for (int r = 0; r < 16; r++) {
      int k = k0w + (r & 3) + 8 * (r >> 2) + 4 * hi32;
      dinv[(size_t)bh * T_ + k] = 1.0f / s[r];
    }
  }
}

// ---- V' = V * dinv, per-head transpose to (bh, HS, T) ----
__global__ __launch_bounds__(256) void transpose_v(
    const ushort_t* __restrict__ QKV, const float* __restrict__ dinv,
    ushort_t* __restrict__ Vt) {
  int t0 = blockIdx.x * 64;
  int bh = blockIdx.y; int b = bh >> 4, h = bh & 15;
  __shared__ ushort_t tile[64][65];
  int tid = threadIdx.x;
  #pragma unroll
  for (int i = 0; i < 16; i++) {
    int idx = i * 256 + tid;
    int tt = idx >> 6, dd = idx & 63;
    float v = bf2f(QKV[(size_t)(b * T_ + t0 + tt) * C3 + 2 * C_ + h * HS_ + dd]);
    tile[tt][dd] = f2bf(v * dinv[(size_t)bh * T_ + t0 + tt]);
  }
  __syncthreads();
  #pragma unroll
  for (int i = 0; i < 16; i++) {
    int idx = i * 256 + tid;
    int dd = idx >> 6, tt = idx & 63;
    Vt[((size_t)(bh * HS_ + dd)) * T_ + t0 + tt] = tile[tt][dd];
  }
}

// ---- PV: block = 4 waves x 32 q-rows. K/V' double-buffered in LDS ----
// att[q,d] = sum_{k<=q} exp2(s') * V'[k,d]. 1-D grid 512: qb=15-(bid&15) big first.
__global__ __launch_bounds__(256) void attn_pv(
    const ushort_t* __restrict__ QKV, const ushort_t* __restrict__ Vt,
    ushort_t* __restrict__ att) {
  int bid = blockIdx.x;
  int qb = 15 - (bid & 15), bh = bid >> 4;
  int b = bh >> 4, h = bh & 15;
  int t = threadIdx.x, w = t >> 6, l = t & 63, l31 = l & 31, hi32 = l >> 5;
  __shared__ ushort_t Ks[2][32 * 64];   // 8KB
  __shared__ ushort_t Vs[2][32 * 64];   // 8KB
  const ushort_t* Qb = QKV + (size_t)b * T_ * C3 + h * HS_;
  const ushort_t* Kb = Qb + C_;
  const ushort_t* Vb = Vt + (size_t)bh * HS_ * T_;
  int q0w = qb * 128 + w * 32;
  short8 qf[4];
  #pragma unroll
  for (int c = 0; c < 4; c++)
    qf[c] = *(const short8*)(Qb + (size_t)(q0w + l31) * C3 + c * 16 + hi32 * 8);
  f32x16 o0 = {}, o1 = {};
  int nkt = qb * 4 + 4;
  int dkt = q0w >> 5;                // wave's diagonal k-tile = qb*4 + w

  int sr = t >> 3, slot = t & 7, su = slot ^ (sr & 7);
  int vdh = su >> 2, vc2 = su & 3;
  const ushort_t* Ksrc = Kb + (size_t)sr * C3 + su * 8;                // + kt*32*C3
  const ushort_t* Vsrc = Vb + (size_t)(vdh * 32 + sr) * T_ + vc2 * 8;  // + kt*32

  gl_lds16(Ksrc, &Ks[0][t * 8]);
  gl_lds16(Vsrc, &Vs[0][t * 8]);
  for (int kt = 0; kt < nkt; kt++) {
    int cur = kt & 1;
    if (kt + 1 < nkt) {
      gl_lds16(Ksrc + (size_t)(kt + 1) * 32 * C3, &Ks[cur ^ 1][t * 8]);
      gl_lds16(Vsrc + (kt + 1) * 32,              &Vs[cur ^ 1][t * 8]);
      asm volatile("s_waitcnt vmcnt(2)");
    } else {
      asm volatile("s_waitcnt vmcnt(0)");
    }
    __builtin_amdgcn_s_barrier();
    __builtin_amdgcn_sched_barrier(0);
    if (kt <= dkt) {
      short8 ka[4], vf[4];
      #pragma unroll
      for (int c = 0; c < 4; c++)
        ka[c] = *(const short8*)&Ks[cur][l31 * 64 + ((c * 2 + hi32) ^ (l31 & 7)) * 8];
      #pragma unroll
      for (int i = 0; i < 4; i++) {
        int u = (i & 1) * 4 + (i >> 1) * 2 + hi32;   // dh*4 + c16*2 + hi32
        vf[i] = *(const short8*)&Vs[cur][l31 * 64 + (u ^ (l31 & 7)) * 8];
      }
      f32x16 sacc = {};
      #pragma unroll
      for (int c = 0; c < 4; c++) sacc = mfma32(ka[c], qf[c], sacc);
      float e[16];
      if (kt == dkt) {               // diagonal: mask k <= q
        int q = q0w + l31;
        #pragma unroll
        for (int r = 0; r < 16; r++) {
          int k = kt * 32 + (r & 3) + 8 * (r >> 2) + 4 * hi32;
          e[r] = (k <= q) ? exp2f(sacc[r]) : 0.f;
        }
      } else {
        #pragma unroll
        for (int r = 0; r < 16; r++) e[r] = exp2f(sacc[r]);
      }
      unsigned u[8];
      #pragma unroll
      for (int j = 0; j < 8; j++) u[j] = pk2(e[2 * j], e[2 * j + 1]);
      pl32swap(u[0], u[2]); pl32swap(u[1], u[3]);
      pl32swap(u[4], u[6]); pl32swap(u[5], u[7]);
      short8 pa0 = mk8(u[0], u[1], u[2], u[3]);
      short8 pa1 = mk8(u[4], u[5], u[6], u[7]);
      o0 = mfma32(pa0, vf[0], o0);   // k 0..15,  d 0..31
      o1 = mfma32(pa0, vf[1], o1);   // k 0..15,  d 32..63
      o0 = mfma32(pa1, vf[2], o0);   // k 16..31, d 0..31
      o1 = mfma32(pa1, vf[3], o1);
    }
    __builtin_amdgcn_sched_barrier(0);
    __builtin_amdgcn_s_barrier();
    __builtin_amdgcn_sched_barrier(0);
  }

  #pragma unroll
  for (int r = 0; r < 16; r++) {
    int q = q0w + (r & 3) + 8 * (r >> 2) + 4 * hi32;
    size_t base = (size_t)(b * T_ + q) * C_ + h * HS_;
    att[base + l31]      = f2bf(o0[r]);
    att[base + 32 + l31] = f2bf(o1[r]);
  }
}

extern "C" void kernel_launch(void* const* d_in, const int* in_sizes, int n_in,
                              void* d_out, int out_size, void* d_ws, size_t ws_size,
                              hipStream_t stream) {
  const float* x   = (const float*)d_in[0];
  const float* Wq  = (const float*)d_in[1];
  const float* bq  = (const float*)d_in[2];
  const float* Wk  = (const float*)d_in[3];
  const float* bk  = (const float*)d_in[4];
  const float* Wv  = (const float*)d_in[5];
  const float* bv  = (const float*)d_in[6];
  const float* Wo  = (const float*)d_in[7];
  const float* bo  = (const float*)d_in[8];
  const float* g1  = (const float*)d_in[9];
  const float* b1  = (const float*)d_in[10];
  const float* g2  = (const float*)d_in[11];
  const float* b2  = (const float*)d_in[12];
  const float* W1  = (const float*)d_in[13];
  const float* bf1 = (const float*)d_in[14];
  const float* W2  = (const float*)d_in[15];
  const float* bf2 = (const float*)d_in[16];
  float* out = (float*)d_out;

  char* base = (char*)d_ws;
  const size_t MB = 1 << 20;
  ushort_t* QKVb  = (ushort_t*)(base);            // 24MB
  ushort_t* hb    = (ushort_t*)(base + 24 * MB);  // 8MB: LN1 out -> att
  ushort_t* Vt    = (ushort_t*)(base + 32 * MB);  // 8MB: V' -> f1b
  float*    y     = (float*)   (base + 40 * MB);  // 16MB
  ushort_t* Wqkvt = (ushort_t*)(base + 56 * MB);  // 6MB
  ushort_t* Wot   = (ushort_t*)(base + 62 * MB);  // 2MB
  ushort_t* W1t   = (ushort_t*)(base + 64 * MB);  // 2MB
  ushort_t* W2t   = (ushort_t*)(base + 66 * MB);  // 2MB
  float*    bqkv  = (float*)   (base + 68 * MB);  // 12KB
  float*    dinv  = (float*)   (base + 68 * MB + 65536); // 256KB

  conv_wqkv3<<<12288, 256, 0, stream>>>(Wq, Wk, Wv, Wqkvt);
  conv_wt3  <<<12288, 256, 0, stream>>>(Wo, W1, W2, Wot);
  bias_cat  <<<12, 256, 0, stream>>>(bq, bk, bv, bqkv);

  ln_bf16<<<NROWS, 256, 0, stream>>>(x, g1, b1, hb);

  gemm128<<<dim3(C3 / 128, NROWS / 128), 256, 0, stream>>>(
      hb, Wqkvt, bqkv, QKVb, NROWS, C3, C_);

  attn_stats<<<512, 256, 0, stream>>>(QKVb, dinv);
  transpose_v<<<dim3(T_ / 64, 32), 256, 0, stream>>>(QKVb, dinv, Vt);
  ushort_t* attb = hb;
  attn_pv<<<512, 256, 0, stream>>>(QKVb, Vt, attb);

  dim3 g64(C_ / 64, NROWS / 128);
  gemm64<0,0,1><<<g64, 256, 0, stream>>>(attb, Wot, bo, x, y, NROWS, C_, C_);

  ushort_t* h2b = QKVb;
  ln_bf16<<<NROWS, 256, 0, stream>>>(y, g2, b2, h2b);
  ushort_t* f1b = Vt;
  gemm64<1,1,0><<<g64, 256, 0, stream>>>(h2b, W1t, bf1, nullptr, f1b, NROWS, C_, C_);
  gemm64<0,0,1><<<g64, 256, 0, stream>>>(f1b, W2t, bf2, y, out, NROWS, C_, C_);
}

// Round 11
// 268.942 us; speedup vs baseline: 1.0755x; 1.0290x over previous
//
#include <hip/hip_runtime.h>
#include <hip/hip_bf16.h>
#include <math.h>

// Transformer block B=2 T=2048 C=1024 H=16 HS=64.
// R11: R10 + (a) XCD-pinned attention grids: xcd=bid&7 serves bh in
// [4*xcd,4*xcd+4) -> 2MB working set per XCD L2 (was: all 32 heads, 16MB,
// FETCH showed 3.4x thrash), (b) 3-buffer 2-deep prefetch, counted
// vmcnt(4)/(2)/(0). Math identical to R9/R10 (absmax-verified).

#define B_   2
#define T_   2048
#define C_   1024
#define H_   16
#define HS_  64
#define NROWS 4096
#define C3   3072
#define K1C  0.1803368801111244f    // 0.125 * log2(e), folded into Q

typedef unsigned short ushort_t;
typedef __attribute__((ext_vector_type(8))) short short8;
typedef __attribute__((ext_vector_type(4))) float f32x4;
typedef __attribute__((ext_vector_type(16))) float f32x16;

__device__ __forceinline__ ushort_t f2bf(float f) {
  __hip_bfloat16 h = __float2bfloat16(f);
  ushort_t u; __builtin_memcpy(&u, &h, 2); return u;
}
__device__ __forceinline__ float bf2f(ushort_t u) {
  union { unsigned u; float f; } v; v.u = ((unsigned)u) << 16;
  return v.f;
}
__device__ __forceinline__ unsigned pk2(float a, float b) {
  __hip_bfloat162 t = __float22bfloat162_rn(make_float2(a, b));
  unsigned u; __builtin_memcpy(&u, &t, 4); return u;
}
__device__ __forceinline__ short8 mk8(unsigned a, unsigned b, unsigned c, unsigned d) {
  union { unsigned u[4]; short8 s; } t;
  t.u[0] = a; t.u[1] = b; t.u[2] = c; t.u[3] = d; return t.s;
}
__device__ __forceinline__ void pl32swap(unsigned &a, unsigned &b) {
  asm("v_permlane32_swap_b32 %0, %1" : "+v"(a), "+v"(b));
}
__device__ __forceinline__ f32x4 mfma16(short8 a, short8 b, f32x4 c) {
  return __builtin_amdgcn_mfma_f32_16x16x32_bf16(a, b, c, 0, 0, 0);
}
__device__ __forceinline__ f32x16 mfma32(short8 a, short8 b, f32x16 c) {
  return __builtin_amdgcn_mfma_f32_32x32x16_bf16(a, b, c, 0, 0, 0);
}
typedef const __attribute__((address_space(1))) void g_void;
typedef __attribute__((address_space(3))) void l_void;
__device__ __forceinline__ void gl_lds16(const void* g, void* l) {
  __builtin_amdgcn_global_load_lds((g_void*)g, (l_void*)l, 16, 0, 0);
}

// ---------------- LayerNorm (f32 in -> bf16 out) ----------------
__global__ __launch_bounds__(256) void ln_bf16(
    const float* __restrict__ x, const float* __restrict__ g,
    const float* __restrict__ b, ushort_t* __restrict__ out) {
  int row = blockIdx.x;
  const float* xr = x + (size_t)row * C_;
  int t = threadIdx.x;
  float4 v = ((const float4*)xr)[t];
  float s  = v.x + v.y + v.z + v.w;
  float ss = v.x*v.x + v.y*v.y + v.z*v.z + v.w*v.w;
  #pragma unroll
  for (int off = 32; off > 0; off >>= 1) {
    s  += __shfl_down(s, off);
    ss += __shfl_down(ss, off);
  }
  __shared__ float red[2][4];
  int wid = t >> 6, lane = t & 63;
  if (lane == 0) { red[0][wid] = s; red[1][wid] = ss; }
  __syncthreads();
  if (t == 0) {
    float a = 0, c = 0;
    for (int i = 0; i < 4; i++) { a += red[0][i]; c += red[1][i]; }
    red[0][0] = a; red[1][0] = c;
  }
  __syncthreads();
  float mean = red[0][0] * (1.0f / C_);
  float var  = red[1][0] * (1.0f / C_) - mean * mean;
  float r = rsqrtf(var + 1e-5f);
  float4 gv = ((const float4*)g)[t];
  float4 bv = ((const float4*)b)[t];
  ushort4 o;
  o.x = f2bf((v.x - mean) * r * gv.x + bv.x);
  o.y = f2bf((v.y - mean) * r * gv.y + bv.y);
  o.z = f2bf((v.z - mean) * r * gv.z + bv.z);
  o.w = f2bf((v.w - mean) * r * gv.w + bv.w);
  ((ushort4*)(out + (size_t)row * C_))[t] = o;
}

// ---- Wq,Wk,Wv (H,C,HS) f32 -> concatenated (3072, 1024) bf16 N-major ----
__global__ __launch_bounds__(256) void conv_wqkv3(
    const float* __restrict__ Wq, const float* __restrict__ Wk,
    const float* __restrict__ Wv, ushort_t* __restrict__ Wt) {
  int idx = blockIdx.x * 256 + threadIdx.x;
  int n = idx >> 10, c = idx & 1023;
  int sel = n >> 10, nn = n & 1023;
  const float* W = (sel == 0) ? Wq : ((sel == 1) ? Wk : Wv);
  Wt[idx] = f2bf(W[((size_t)(nn >> 6) * C_ + c) * HS_ + (nn & 63)]);
}

// ---- Wo,W1,W2 (K,N) f32 -> three contiguous (N,K) bf16 blocks ----
__global__ __launch_bounds__(256) void conv_wt3(
    const float* __restrict__ W0, const float* __restrict__ W1,
    const float* __restrict__ W2, ushort_t* __restrict__ Wt) {
  int idx = blockIdx.x * 256 + threadIdx.x;
  int sel = idx >> 20, rem = idx & 1048575;
  int n = rem >> 10, k = rem & 1023;
  const float* W = (sel == 0) ? W0 : ((sel == 1) ? W1 : W2);
  Wt[idx] = f2bf(W[(size_t)k * C_ + n]);
}

__global__ __launch_bounds__(256) void bias_cat(
    const float* __restrict__ bq, const float* __restrict__ bk,
    const float* __restrict__ bv, float* __restrict__ out) {
  int i = blockIdx.x * 256 + threadIdx.x;
  if (i < 3072)
    out[i] = (i < 1024) ? bq[i] : ((i < 2048) ? bk[i - 1024] : bv[i - 2048]);
}

// -------- GEMM 128x128 tile (QKV, N=3072); Q third scaled by K1C --------
__global__ __launch_bounds__(256) void gemm128(
    const ushort_t* __restrict__ A, const ushort_t* __restrict__ Bt,
    const float* __restrict__ bias, ushort_t* __restrict__ Cm,
    int M, int N, int K) {
  __shared__ ushort_t As[128 * 32];
  __shared__ ushort_t Bs[128 * 32];
  int t = threadIdx.x;
  int m0 = blockIdx.y * 128, n0 = blockIdx.x * 128;
  int w = t >> 6, l = t & 63;
  int wr = w >> 1, wc = w & 1;
  int lo = l & 15, hi = l >> 4;
  f32x4 acc[4][4] = {};
  int srow = t >> 2, scol = (t & 3) * 8;
  const ushort_t* Ag = A  + (size_t)(m0 + srow) * K + scol;
  const ushort_t* Bg = Bt + (size_t)(n0 + srow) * K + scol;
  ushort_t* AsP = As + t * 8;
  ushort_t* BsP = Bs + t * 8;
  for (int k0 = 0; k0 < K; k0 += 32) {
    gl_lds16(Ag + k0,          AsP);
    gl_lds16(Ag + 64 * K + k0, AsP + 64 * 32);
    gl_lds16(Bg + k0,          BsP);
    gl_lds16(Bg + 64 * K + k0, BsP + 64 * 32);
    __syncthreads();
    short8 af[4], bfr[4];
    #pragma unroll
    for (int i = 0; i < 4; i++)
      af[i] = *(const short8*)&As[(wr * 64 + i * 16 + lo) * 32 + hi * 8];
    #pragma unroll
    for (int j = 0; j < 4; j++)
      bfr[j] = *(const short8*)&Bs[(wc * 64 + j * 16 + lo) * 32 + hi * 8];
    #pragma unroll
    for (int i = 0; i < 4; i++)
      #pragma unroll
      for (int j = 0; j < 4; j++)
        acc[i][j] = mfma16(af[i], bfr[j], acc[i][j]);
    __syncthreads();
  }
  float qs = (n0 < C_) ? K1C : 1.0f;
  #pragma unroll
  for (int i = 0; i < 4; i++) {
    int m = m0 + wr * 64 + i * 16 + hi * 4;
    #pragma unroll
    for (int j = 0; j < 4; j++) {
      int n = n0 + wc * 64 + j * 16 + lo;
      float bv = bias[n];
      #pragma unroll
      for (int r = 0; r < 4; r++)
        Cm[(size_t)(m + r) * N + n] = f2bf((acc[i][j][r] + bv) * qs);
    }
  }
}

// ---------------- GEMM 128x64 tile (N=1024 GEMMs) ----------------
template<int OUT_BF16, int RELU, int HAS_RES>
__global__ __launch_bounds__(256) void gemm64(
    const ushort_t* __restrict__ A, const ushort_t* __restrict__ Bt,
    const float* __restrict__ bias, const float* __restrict__ res,
    void* __restrict__ Cm, int M, int N, int K) {
  __shared__ ushort_t As[128 * 32];
  __shared__ ushort_t Bs[64 * 32];
  int t = threadIdx.x;
  int m0 = blockIdx.y * 128, n0 = blockIdx.x * 64;
  int w = t >> 6, l = t & 63;
  int wr = w >> 1, wc = w & 1;
  int lo = l & 15, hi = l >> 4;
  f32x4 acc[4][2] = {};
  int srow = t >> 2, scol = (t & 3) * 8;
  const ushort_t* Ag = A  + (size_t)(m0 + srow) * K + scol;
  const ushort_t* Bg = Bt + (size_t)(n0 + srow) * K + scol;
  ushort_t* AsP = As + t * 8;
  ushort_t* BsP = Bs + t * 8;
  for (int k0 = 0; k0 < K; k0 += 32) {
    gl_lds16(Ag + k0,          AsP);
    gl_lds16(Ag + 64 * K + k0, AsP + 64 * 32);
    gl_lds16(Bg + k0,          BsP);
    __syncthreads();
    short8 af[4], bfr[2];
    #pragma unroll
    for (int i = 0; i < 4; i++)
      af[i] = *(const short8*)&As[(wr * 64 + i * 16 + lo) * 32 + hi * 8];
    #pragma unroll
    for (int j = 0; j < 2; j++)
      bfr[j] = *(const short8*)&Bs[(wc * 32 + j * 16 + lo) * 32 + hi * 8];
    #pragma unroll
    for (int i = 0; i < 4; i++)
      #pragma unroll
      for (int j = 0; j < 2; j++)
        acc[i][j] = mfma16(af[i], bfr[j], acc[i][j]);
    __syncthreads();
  }
  #pragma unroll
  for (int i = 0; i < 4; i++) {
    int m = m0 + wr * 64 + i * 16 + hi * 4;
    #pragma unroll
    for (int j = 0; j < 2; j++) {
      int n = n0 + wc * 32 + j * 16 + lo;
      float bv = bias[n];
      #pragma unroll
      for (int r = 0; r < 4; r++) {
        float v = acc[i][j][r] + bv;
        if (HAS_RES) v += res[(size_t)(m + r) * N + n];
        if (RELU) v = fmaxf(v, 0.f);
        if (OUT_BF16) ((ushort_t*)Cm)[(size_t)(m + r) * N + n] = f2bf(v);
        else          ((float*)Cm)[(size_t)(m + r) * N + n] = v;
      }
    }
  }
}

// ---- stats: 4 waves x 32 k-rows, Q tiles 3-buffered. XCD-pinned grid ----
// bid: xcd=bid&7, q=bid>>3; bh=xcd*4+(q&3); kb=q>>2 (kb=0 biggest, first).
__global__ __launch_bounds__(256) void attn_stats(
    const ushort_t* __restrict__ QKV, float* __restrict__ dinv) {
  int bid = blockIdx.x;
  int xcd = bid & 7, q = bid >> 3;
  int bh = xcd * 4 + (q & 3);
  int kb = q >> 2;
  int b = bh >> 4, h = bh & 15;
  int t = threadIdx.x, w = t >> 6, l = t & 63, l31 = l & 31, hi32 = l >> 5;
  __shared__ ushort_t Qs[3][32 * 64];   // 12KB, 3-buffered
  const ushort_t* Qb = QKV + (size_t)b * T_ * C3 + h * HS_;
  const ushort_t* Kb = Qb + C_;
  int k0w = kb * 128 + w * 32;
  short8 ka[4];
  #pragma unroll
  for (int c = 0; c < 4; c++)
    ka[c] = *(const short8*)(Kb + (size_t)(k0w + l31) * C3 + c * 16 + hi32 * 8);
  float s[16];
  #pragma unroll
  for (int r = 0; r < 16; r++) s[r] = 0.f;

  int sr = t >> 3, slot = t & 7, su = slot ^ (sr & 7);
  const ushort_t* Qsrc = Qb + (size_t)sr * C3 + su * 8;   // + qt*32*C3
  int qt0 = kb * 4, cnt = 64 - qt0;
  int dqt = qt0 + w;                 // wave's diagonal q-tile

  gl_lds16(Qsrc + (size_t)qt0 * 32 * C3, &Qs[0][t * 8]);
  if (cnt > 1) gl_lds16(Qsrc + (size_t)(qt0 + 1) * 32 * C3, &Qs[1][t * 8]);
  for (int i = 0; i < cnt; i++) {
    int qt = qt0 + i;
    int cur = i % 3;
    if (i + 2 < cnt) {
      gl_lds16(Qsrc + (size_t)(qt + 2) * 32 * C3, &Qs[(i + 2) % 3][t * 8]);
      asm volatile("s_waitcnt vmcnt(2)");
    } else if (i + 1 < cnt) {
      asm volatile("s_waitcnt vmcnt(1)");
    } else {
      asm volatile("s_waitcnt vmcnt(0)");
    }
    __builtin_amdgcn_s_barrier();
    __builtin_amdgcn_sched_barrier(0);
    if (qt >= dqt) {
      short8 qf[4];
      #pragma unroll
      for (int c = 0; c < 4; c++)
        qf[c] = *(const short8*)&Qs[cur][l31 * 64 + ((c * 2 + hi32) ^ (l31 & 7)) * 8];
      f32x16 d = {};
      #pragma unroll
      for (int c = 0; c < 4; c++) d = mfma32(ka[c], qf[c], d);
      if (qt == dqt) {               // diagonal: mask q >= k
        int qq = qt * 32 + l31;
        #pragma unroll
        for (int r = 0; r < 16; r++) {
          int k = k0w + (r & 3) + 8 * (r >> 2) + 4 * hi32;
          s[r] += (qq >= k) ? exp2f(d[r]) : 0.f;
        }
      } else {
        #pragma unroll
        for (int r = 0; r < 16; r++) s[r] += exp2f(d[r]);
      }
    }
    __builtin_amdgcn_sched_barrier(0);
    __builtin_amdgcn_s_barrier();
    __builtin_amdgcn_sched_barrier(0);
  }
  #pragma unroll
  for (int off = 1; off < 32; off <<= 1)
    #pragma unroll
    for (int r = 0; r < 16; r++)
      s[r] += __shfl_xor(s[r], off);
  if (l31 == 0) {
    #pragma unroll
    for (int r = 0; r < 16; r++) {
      int k = k0w + (r & 3) + 8 * (r >> 2) + 4 * hi32;
      dinv[(size_t)bh * T_ + k] = 1.0f / s[r];
    }
  }
}

// ---- V' = V * dinv, per-head transpose to (bh, HS, T) ----
__global__ __launch_bounds__(256) void transpose_v(
    const ushort_t* __restrict__ QKV, const float* __restrict__ dinv,
    ushort_t* __restrict__ Vt) {
  int t0 = blockIdx.x * 64;
  int bh = blockIdx.y; int b = bh >> 4, h = bh & 15;
  __shared__ ushort_t tile[64][65];
  int tid = threadIdx.x;
  #pragma unroll
  for (int i = 0; i < 16; i++) {
    int idx = i * 256 + tid;
    int tt = idx >> 6, dd = idx & 63;
    float v = bf2f(QKV[(size_t)(b * T_ + t0 + tt) * C3 + 2 * C_ + h * HS_ + dd]);
    tile[tt][dd] = f2bf(v * dinv[(size_t)bh * T_ + t0 + tt]);
  }
  __syncthreads();
  #pragma unroll
  for (int i = 0; i < 16; i++) {
    int idx = i * 256 + tid;
    int dd = idx >> 6, tt = idx & 63;
    Vt[((size_t)(bh * HS_ + dd)) * T_ + t0 + tt] = tile[tt][dd];
  }
}

// ---- PV: 4 waves x 32 q-rows, K/V' 3-buffered. XCD-pinned grid ----
// bid: xcd=bid&7, q=bid>>3; bh=xcd*4+(q&3); qb=15-(q>>2) (big first).
__global__ __launch_bounds__(256) void attn_pv(
    const ushort_t* __restrict__ QKV, const ushort_t* __restrict__ Vt,
    ushort_t* __restrict__ att) {
  int bid = blockIdx.x;
  int xcd = bid & 7, q = bid >> 3;
  int bh = xcd * 4 + (q & 3);
  int qb = 15 - (q >> 2);
  int b = bh >> 4, h = bh & 15;
  int t = threadIdx.x, w = t >> 6, l = t & 63, l31 = l & 31, hi32 = l >> 5;
  __shared__ ushort_t Ks[3][32 * 64];   // 12KB
  __shared__ ushort_t Vs[3][32 * 64];   // 12KB
  const ushort_t* Qb = QKV + (size_t)b * T_ * C3 + h * HS_;
  const ushort_t* Kb = Qb + C_;
  const ushort_t* Vb = Vt + (size_t)bh * HS_ * T_;
  int q0w = qb * 128 + w * 32;
  short8 qf[4];
  #pragma unroll
  for (int c = 0; c < 4; c++)
    qf[c] = *(const short8*)(Qb + (size_t)(q0w + l31) * C3 + c * 16 + hi32 * 8);
  f32x16 o0 = {}, o1 = {};
  int nkt = qb * 4 + 4;
  int dkt = q0w >> 5;                // wave's diagonal k-tile = qb*4 + w

  int sr = t >> 3, slot = t & 7, su = slot ^ (sr & 7);
  int vdh = su >> 2, vc2 = su & 3;
  const ushort_t* Ksrc = Kb + (size_t)sr * C3 + su * 8;                // + kt*32*C3
  const ushort_t* Vsrc = Vb + (size_t)(vdh * 32 + sr) * T_ + vc2 * 8;  // + kt*32

  gl_lds16(Ksrc, &Ks[0][t * 8]);
  gl_lds16(Vsrc, &Vs[0][t * 8]);
  if (nkt > 1) {
    gl_lds16(Ksrc + (size_t)32 * C3, &Ks[1][t * 8]);
    gl_lds16(Vsrc + 32,              &Vs[1][t * 8]);
  }
  for (int kt = 0; kt < nkt; kt++) {
    int cur = kt % 3;
    if (kt + 2 < nkt) {
      gl_lds16(Ksrc + (size_t)(kt + 2) * 32 * C3, &Ks[(kt + 2) % 3][t * 8]);
      gl_lds16(Vsrc + (kt + 2) * 32,              &Vs[(kt + 2) % 3][t * 8]);
      asm volatile("s_waitcnt vmcnt(4)");
    } else if (kt + 1 < nkt) {
      asm volatile("s_waitcnt vmcnt(2)");
    } else {
      asm volatile("s_waitcnt vmcnt(0)");
    }
    __builtin_amdgcn_s_barrier();
    __builtin_amdgcn_sched_barrier(0);
    if (kt <= dkt) {
      short8 ka[4], vf[4];
      #pragma unroll
      for (int c = 0; c < 4; c++)
        ka[c] = *(const short8*)&Ks[cur][l31 * 64 + ((c * 2 + hi32) ^ (l31 & 7)) * 8];
      #pragma unroll
      for (int i = 0; i < 4; i++) {
        int u = (i & 1) * 4 + (i >> 1) * 2 + hi32;   // dh*4 + c16*2 + hi32
        vf[i] = *(const short8*)&Vs[cur][l31 * 64 + (u ^ (l31 & 7)) * 8];
      }
      f32x16 sacc = {};
      #pragma unroll
      for (int c = 0; c < 4; c++) sacc = mfma32(ka[c], qf[c], sacc);
      float e[16];
      if (kt == dkt) {               // diagonal: mask k <= q
        int qq = q0w + l31;
        #pragma unroll
        for (int r = 0; r < 16; r++) {
          int k = kt * 32 + (r & 3) + 8 * (r >> 2) + 4 * hi32;
          e[r] = (k <= qq) ? exp2f(sacc[r]) : 0.f;
        }
      } else {
        #pragma unroll
        for (int r = 0; r < 16; r++) e[r] = exp2f(sacc[r]);
      }
      unsigned u[8];
      #pragma unroll
      for (int j = 0; j < 8; j++) u[j] = pk2(e[2 * j], e[2 * j + 1]);
      pl32swap(u[0], u[2]); pl32swap(u[1], u[3]);
      pl32swap(u[4], u[6]); pl32swap(u[5], u[7]);
      short8 pa0 = mk8(u[0], u[1], u[2], u[3]);
      short8 pa1 = mk8(u[4], u[5], u[6], u[7]);
      o0 = mfma32(pa0, vf[0], o0);   // k 0..15,  d 0..31
      o1 = mfma32(pa0, vf[1], o1);   // k 0..15,  d 32..63
      o0 = mfma32(pa1, vf[2], o0);   // k 16..31, d 0..31
      o1 = mfma32(pa1, vf[3], o1);
    }
    __builtin_amdgcn_sched_barrier(0);
    __builtin_amdgcn_s_barrier();
    __builtin_amdgcn_sched_barrier(0);
  }

  #pragma unroll
  for (int r = 0; r < 16; r++) {
    int qq = q0w + (r & 3) + 8 * (r >> 2) + 4 * hi32;
    size_t base = (size_t)(b * T_ + qq) * C_ + h * HS_;
    att[base + l31]      = f2bf(o0[r]);
    att[base + 32 + l31] = f2bf(o1[r]);
  }
}

extern "C" void kernel_launch(void* const* d_in, const int* in_sizes, int n_in,
                              void* d_out, int out_size, void* d_ws, size_t ws_size,
                              hipStream_t stream) {
  const float* x   = (const float*)d_in[0];
  const float* Wq  = (const float*)d_in[1];
  const float* bq  = (const float*)d_in[2];
  const float* Wk  = (const float*)d_in[3];
  const float* bk  = (const float*)d_in[4];
  const float* Wv  = (const float*)d_in[5];
  const float* bv  = (const float*)d_in[6];
  const float* Wo  = (const float*)d_in[7];
  const float* bo  = (const float*)d_in[8];
  const float* g1  = (const float*)d_in[9];
  const float* b1  = (const float*)d_in[10];
  const float* g2  = (const float*)d_in[11];
  const float* b2  = (const float*)d_in[12];
  const float* W1  = (const float*)d_in[13];
  const float* bf1 = (const float*)d_in[14];
  const float* W2  = (const float*)d_in[15];
  const float* bf2 = (const float*)d_in[16];
  float* out = (float*)d_out;

  char* base = (char*)d_ws;
  const size_t MB = 1 << 20;
  ushort_t* QKVb  = (ushort_t*)(base);            // 24MB
  ushort_t* hb    = (ushort_t*)(base + 24 * MB);  // 8MB: LN1 out -> att
  ushort_t* Vt    = (ushort_t*)(base + 32 * MB);  // 8MB: V' -> f1b
  float*    y     = (float*)   (base + 40 * MB);  // 16MB
  ushort_t* Wqkvt = (ushort_t*)(base + 56 * MB);  // 6MB
  ushort_t* Wot   = (ushort_t*)(base + 62 * MB);  // 2MB
  ushort_t* W1t   = (ushort_t*)(base + 64 * MB);  // 2MB
  ushort_t* W2t   = (ushort_t*)(base + 66 * MB);  // 2MB
  float*    bqkv  = (float*)   (base + 68 * MB);  // 12KB
  float*    dinv  = (float*)   (base + 68 * MB + 65536); // 256KB

  conv_wqkv3<<<12288, 256, 0, stream>>>(Wq, Wk, Wv, Wqkvt);
  conv_wt3  <<<12288, 256, 0, stream>>>(Wo, W1, W2, Wot);
  bias_cat  <<<12, 256, 0, stream>>>(bq, bk, bv, bqkv);

  ln_bf16<<<NROWS, 256, 0, stream>>>(x, g1, b1, hb);

  gemm128<<<dim3(C3 / 128, NROWS / 128), 256, 0, stream>>>(
      hb, Wqkvt, bqkv, QKVb, NROWS, C3, C_);

  attn_stats<<<512, 256, 0, stream>>>(QKVb, dinv);
  transpose_v<<<dim3(T_ / 64, 32), 256, 0, stream>>>(QKVb, dinv, Vt);
  ushort_t* attb = hb;
  attn_pv<<<512, 256, 0, stream>>>(QKVb, Vt, attb);

  dim3 g64(C_ / 64, NROWS / 128);
  gemm64<0,0,1><<<g64, 256, 0, stream>>>(attb, Wot, bo, x, y, NROWS, C_, C_);

  ushort_t* h2b = QKVb;
  ln_bf16<<<NROWS, 256, 0, stream>>>(y, g2, b2, h2b);
  ushort_t* f1b = Vt;
  gemm64<1,1,0><<<g64, 256, 0, stream>>>(h2b, W1t, bf1, nullptr, f1b, NROWS, C_, C_);
  gemm64<0,0,1><<<g64, 256, 0, stream>>>(f1b, W2t, bf2, y, out, NROWS, C_, C_);
}